// Round 5
// baseline (105.013 us; speedup 1.0000x reference)
//
#include <hip/hip_runtime.h>

// Problem: 2048x2048 image, P Gaussian peaks splatted into (ws x ws) windows
// at rounded integer centers + 0.1 background. ws = int(5*max(width)) odd-adj.
//
// R7: separability -> per-64x64-region GEMM C[r][c]=sum_k A[k][r]*B[k][c] via
//     mfma_f32_16x16x32_f16. Harness floor ~87us (2x 256MiB 0xAA re-poison
//     fills @ ~43us each, 76-78% HBM peak = achievable ceiling).
// R9/R11: direct per-region binning (width<4.0 => half<=9) + compact-list LDS
//     stage. 118.8/115.5us.
// R12: k_bin contention fix (4-way sub-buckets, independent predicated
//     atomics) -> 104.9us. Contention confirmed as the dominant controllable
//     cost (λ=80 -> 20 per address gave -10.6us).
// R13: (1) SUB 4->8 (λ=10/address; SCAP=40, overflow P~5e-13/bucket);
//     (2) KMAX 96->128: render blocks are all co-resident (4/CU), so the
//     3.6% of regions needing a 2nd pass (nc>96) set render's finish line;
//     KMAX=128 makes single-pass P ~= 1-3e-7. LDS 37.9KB keeps 4 blocks/CU.
//     Numerics untouched.

#define IMG_W 2048
#define IMG_H 2048
#define REG 64                  // region edge (px), one block per region
#define REGS_X (IMG_W / REG)    // 32
#define NREG (REGS_X * REGS_X)  // 1024
#define SUB 8                   // sub-buckets per region (contention split)
#define SCAP 40                 // slots/sub-bucket; Poisson(10) tail ~5e-13
#define RCAP (SUB * SCAP)       // 320 list slots/region
#define HALO 9                  // width < 4.0 strictly -> wsz <= 19 -> half <= 9
#define KCH 4                   // LDS K-chunks resident
#define KMAX (KCH * 32)         // 128 k per pass -> single-pass P ~= 1
#define CH 32                   // K-chunk per MFMA step

typedef _Float16 half8 __attribute__((ext_vector_type(8)));
typedef float floatx4 __attribute__((ext_vector_type(4)));

// Bin peaks directly into per-region sub-bucketed lists (conservative halo=9)
// + global width max (fused one pass).
__global__ void k_bin(const float* __restrict__ px, const float* __restrict__ py,
                      const float* __restrict__ ht, const float* __restrict__ wd,
                      int P, int* __restrict__ rcnt, unsigned int* __restrict__ wmax,
                      float4* __restrict__ lists) {
    int i = blockIdx.x * blockDim.x + threadIdx.x;
    bool live = (i < P);
    float w = live ? wd[i] : 0.0f;          // widths > 0; 0 is identity for max
    float wr = w;
    for (int m = 32; m >= 1; m >>= 1)
        wr = fmaxf(wr, __shfl_xor(wr, m));
    if ((threadIdx.x & 63) == 0)
        atomicMax(wmax, __float_as_uint(wr)); // positive floats: bit order == order
    if (!live) return;
    float cxf = rintf(px[i]);               // rintf = round-half-even = jnp.round
    float cyf = rintf(py[i]);
    int cxi = (int)cxf, cyi = (int)cyf;
    float4 rec = make_float4(cxf, cyf, ht[i], -0.5f / (w * w));
    // region rx overlaps window iff 64*rx in [cxi-half-63, cxi+half]; half<=9.
    int rx0 = (cxi - HALO) >> 6, rx1 = (cxi + HALO) >> 6;   // >>6 floors
    int ry0 = (cyi - HALO) >> 6, ry1 = (cyi + HALO) >> 6;
    rx0 = max(rx0, 0); rx1 = min(rx1, REGS_X - 1);
    ry0 = max(ry0, 0); ry1 = min(ry1, REGS_X - 1);
    int sub = i & (SUB - 1);
    bool tx = (rx1 != rx0), ty = (ry1 != ry0);
    int b00 = (ry0 * REGS_X + rx0) * SUB + sub;
    int b01 = (ry0 * REGS_X + rx1) * SUB + sub;
    int b10 = (ry1 * REGS_X + rx0) * SUB + sub;
    int b11 = (ry1 * REGS_X + rx1) * SUB + sub;
    // 4 INDEPENDENT predicated atomics, issued back-to-back (no chaining):
    int s0 = atomicAdd(&rcnt[b00], 1);
    int s1 = tx         ? atomicAdd(&rcnt[b01], 1) : SCAP;
    int s2 = ty         ? atomicAdd(&rcnt[b10], 1) : SCAP;
    int s3 = (tx && ty) ? atomicAdd(&rcnt[b11], 1) : SCAP;
    if (s0 < SCAP) lists[(size_t)(b00 >> 3) * RCAP + (b00 & 7) * SCAP + s0] = rec;
    if (s1 < SCAP) lists[(size_t)(b01 >> 3) * RCAP + (b01 & 7) * SCAP + s1] = rec;
    if (s2 < SCAP) lists[(size_t)(b10 >> 3) * RCAP + (b10 & 7) * SCAP + s2] = rec;
    if (s3 < SCAP) lists[(size_t)(b11 >> 3) * RCAP + (b11 & 7) * SCAP + s3] = rec;
}

__global__ __launch_bounds__(512) void k_render(
    const int* __restrict__ rcnt, const float4* __restrict__ lists,
    const unsigned int* __restrict__ wmax, float* __restrict__ out)
{
    // [chunk][oct][row][8] f16: build writes half8 at byte (chunk*4+oct)*1024
    // + row*16 (contiguous per wave); frag read is 256B-contiguous per
    // 16-lane group. Both conflict-free. 16,384 B per side + cand 5,120 B
    // = 37.9 KB -> 4 blocks/CU.
    __shared__ _Float16 Af[KCH * 4 * REG * 8];   // row factors (y)
    __shared__ _Float16 Bf[KCH * 4 * REG * 8];   // col factors (x), ht folded
    __shared__ float4 cand[RCAP];                // staged compact list

    int flat = threadIdx.x;
    int wave = flat >> 6;
    int lane = flat & 63;

    // window half-size, exactly as reference: int(5*float64(max_w)), odd-adj.
    float wm = __uint_as_float(*wmax);
    int wsz = (int)(5.0 * (double)wm);
    if ((wsz & 1) == 0) wsz++;
    float halff = (float)(wsz >> 1);

    int RX0 = blockIdx.x * REG;
    int RY0 = blockIdx.y * REG;
    int rgn = blockIdx.y * REGS_X + blockIdx.x;
    int4 cva = *(const int4*)&rcnt[rgn * SUB];       // 32B-aligned, uniform
    int4 cvb = *(const int4*)&rcnt[rgn * SUB + 4];
    int c0 = min(cva.x, SCAP), c1 = min(cva.y, SCAP);
    int c2 = min(cva.z, SCAP), c3 = min(cva.w, SCAP);
    int c4 = min(cvb.x, SCAP), c5 = min(cvb.y, SCAP);
    int c6 = min(cvb.z, SCAP), c7 = min(cvb.w, SCAP);
    int o1 = c0, o2 = o1 + c1, o3 = o2 + c2, o4 = o3 + c3;
    int o5 = o4 + c4, o6 = o5 + c5, o7 = o6 + c6;
    int nc = o7 + c7;
    const float4* __restrict__ cl = &lists[(size_t)rgn * RCAP];

    // ---- stage: sub-bucket compaction, one coalesced load, no atomics.
    // Valid entries -> cand[0..nc); sentinels -> cand[nc..RCAP). Disjoint.
    // Sentinel (1e9,...): d ~ -1e9 fails fabs(d)<=halff -> factor exactly 0.
    if (flat < RCAP) {
        float4 v = cl[flat];
        int s = flat / SCAP;                 // const divisor -> magic mul
        int j = flat - s * SCAP;
        int off = s < 4 ? (s < 2 ? (s == 0 ? 0  : o1) : (s == 2 ? o2 : o3))
                        : (s < 6 ? (s == 4 ? o4 : o5) : (s == 6 ? o6 : o7));
        int cs  = s < 4 ? (s < 2 ? (s == 0 ? c0 : c1) : (s == 2 ? c2 : c3))
                        : (s < 6 ? (s == 4 ? c4 : c5) : (s == 6 ? c6 : c7));
        if (j < cs) cand[off + j] = v;
        if (flat >= nc) cand[flat] = make_float4(1e9f, 1e9f, 0.f, 0.f);
    }
    __syncthreads();

    // wave handles output tiles t=wave and t+8: m=(t&3)*16, n=(t>>2)*16.
    // mfma_f32_16x16x32_f16 frags: A[m=lane&15][k=quad*8+j],
    // B[k=quad*8+j][n=lane&15]; C/D: col=lane&15, row=quad*4+reg.
    floatx4 acc0 = {0.f, 0.f, 0.f, 0.f};
    floatx4 acc1 = {0.f, 0.f, 0.f, 0.f};
    int m0 = (wave & 3) * 16,       n0 = (wave >> 2) * 16;
    int m1 = ((wave + 8) & 3) * 16, n1 = ((wave + 8) >> 2) * 16;
    int fr = lane & 15;             // frag spatial index
    int quad = lane >> 4;           // frag k-octet

    // build roles: waves 0-3 -> A (rows/y), waves 4-7 -> B (cols/x);
    // oct = wave&3 covers k sub-range [ci*32+oct*8, +8). Lane owns spatial
    // coord `lane`; 8 k-values in regs -> ONE contiguous ds_write_b128.
    int side = wave >> 2;           // 0 = A, 1 = B
    int oct = wave & 3;
    float dbase = (side ? (float)RX0 : (float)RY0) + (float)lane;
    _Float16* __restrict__ fdst = side ? Bf : Af;

    int passes = (nc + KMAX - 1) / KMAX;     // 0 if region empty
    for (int p = 0; p < passes; ++p) {
        int base = p * KMAX;
        int rem = min(nc - base, KMAX);
        int nch = (rem + CH - 1) / CH;       // <= KCH
        if (p) __syncthreads();              // ~never: protect LDS reuse
        for (int ci = 0; ci < nch; ++ci) {
            half8 hv;
            int k0 = base + ci * CH + oct * 8;
            #pragma unroll
            for (int t = 0; t < 8; ++t) {
                float4 q = cand[k0 + t];     // wave-uniform -> LDS broadcast
                float d = dbase - (side ? q.x : q.y);
                float val = 0.0f;
                if (fabsf(d) <= halff) {
                    val = __expf(q.w * d * d);
                    if (side) val *= q.z;    // fold height into B
                }
                hv[t] = (_Float16)val;
            }
            *(half8*)&fdst[((ci * 4 + oct) * REG + lane) * 8] = hv;
        }
        __syncthreads();                     // build done -> mfma
        for (int ci = 0; ci < nch; ++ci) {
            const _Float16* ab = &Af[((ci * 4 + quad) * REG) * 8];
            const _Float16* bb = &Bf[((ci * 4 + quad) * REG) * 8];
            half8 a0 = *(const half8*)&ab[(m0 + fr) * 8];
            half8 b0 = *(const half8*)&bb[(n0 + fr) * 8];
            acc0 = __builtin_amdgcn_mfma_f32_16x16x32_f16(a0, b0, acc0, 0, 0, 0);
            half8 a1 = *(const half8*)&ab[(m1 + fr) * 8];
            half8 b1 = *(const half8*)&bb[(n1 + fr) * 8];
            acc1 = __builtin_amdgcn_mfma_f32_16x16x32_f16(a1, b1, acc1, 0, 0, 0);
        }
    }

    // ---- epilogue: background + store (C/D layout: col=lane&15, row=q*4+r)
    int col = fr;
    int qr = quad * 4;
    {
        size_t gx = (size_t)(RX0 + n0 + col);
        size_t gy = (size_t)(RY0 + m0 + qr);
        for (int r = 0; r < 4; ++r)
            out[(gy + r) * IMG_W + gx] = acc0[r] + 0.1f;
    }
    {
        size_t gx = (size_t)(RX0 + n1 + col);
        size_t gy = (size_t)(RY0 + m1 + qr);
        for (int r = 0; r < 4; ++r)
            out[(gy + r) * IMG_W + gx] = acc1[r] + 0.1f;
    }
}

extern "C" void kernel_launch(void* const* d_in, const int* in_sizes, int n_in,
                              void* d_out, int out_size, void* d_ws, size_t ws_size,
                              hipStream_t stream) {
    // inputs: 0:X 1:Y 2:pos_x 3:pos_y 4:height 5:width (X/Y unused: X[0,0]=Y[0,0]=0)
    const float* pos_x  = (const float*)d_in[2];
    const float* pos_y  = (const float*)d_in[3];
    const float* height = (const float*)d_in[4];
    const float* width  = (const float*)d_in[5];
    int P = in_sizes[2];
    float* out = (float*)d_out;
    char* ws = (char*)d_ws;

    // layout: [wmax pad16 | rcnt NREG*SUB*4 | lists NREG*RCAP*16]  (~5.3 MB)
    unsigned int* wmax = (unsigned int*)ws;
    int* rcnt = (int*)(ws + 16);
    size_t lists_off = 16 + sizeof(int) * (size_t)(NREG * SUB); // 32784, 16-al
    float4* lists = (float4*)(ws + lists_off);

    hipMemsetAsync(ws, 0, lists_off, stream);             // wmax + rcnt only
    k_bin<<<(P + 255) / 256, 256, 0, stream>>>(pos_x, pos_y, height, width, P,
                                               rcnt, wmax, lists);
    dim3 grid(REGS_X, REGS_X), block(512);
    k_render<<<grid, block, 0, stream>>>(rcnt, lists, wmax, out);
}